// Round 2
// baseline (151.717 us; speedup 1.0000x reference)
//
#include <hip/hip_runtime.h>
#include <hip/hip_bf16.h>
#include <stdint.h>
#include <stddef.h>

typedef unsigned short u16;
typedef unsigned int   u32;
typedef __attribute__((ext_vector_type(8))) short bf16x8;  // 8 bf16 = 4 VGPRs
typedef __attribute__((ext_vector_type(4))) float f32x4;   // MFMA C/D

#define LOG2E   1.44269504f
#define EXP_OFF 23.0831206f   // 16 * log2(e)

static __device__ __forceinline__ float bf2f(u16 v) {
    u32 u = ((u32)v) << 16; float f; __builtin_memcpy(&f, &u, 4); return f;
}
static __device__ __forceinline__ u16 f2bf(float f) {
    u32 u; __builtin_memcpy(&u, &f, 4);
    u32 r = (u + 0x7fffu + ((u >> 16) & 1u)) >> 16; return (u16)r;
}
static __device__ __forceinline__ float as_f(u32 u) { float f; __builtin_memcpy(&f, &u, 4); return f; }
static __device__ __forceinline__ u32   as_u(float f) { u32 u; __builtin_memcpy(&u, &f, 4); return u; }

// fp32-vs-bf16 input detection (wave 0)
static __device__ __forceinline__ int detect_f32_wave0(const void* x, int t) {
    const u32* xw = (const u32*)x;
    int bad = 0;
    #pragma unroll
    for (int k = 0; k < 4; ++k) {
        u32 wv = xw[(t << 2) + k];
        int e = (wv >> 7) & 0xff;
        bad += (e >= 160);
    }
    unsigned long long m = __ballot(bad > 0);
    return (__popcll(m) >= 8) ? 1 : 0;
}

// V workspace layout (pre-fragmented for MFMA B-operand, per batch):
//   elem_addr = cblk*65536 + jblk*512 + (quad4*16 + clo)*8 + jlo
//   where c = cblk*16 + clo, j = jblk*32 + quad4*8 + jlo.
// A wave B-frag load (lane = quad*16+n16 reads 16B) is 1KB fully contiguous.

// ---------------------------------------------------------------------------
// Kernel 1 (MFMA proj, unchanged from R1 — verified):
//   Grid = (it*5 + g)*4 + n : 64 i-tiles x 5 och-groups(64) x 4 batches.
//   W-slice staged once to LDS bf16 XOR-swizzled; A (x) direct from global,
//   prefetched one k-chunk ahead; no k-loop barriers.
// ---------------------------------------------------------------------------
__global__ __launch_bounds__(256) void qkv_proj_mfma(
    const void* __restrict__ x,
    const void* __restrict__ Wq, const void* __restrict__ bq,
    const void* __restrict__ Wk, const void* __restrict__ bk,
    const void* __restrict__ Wv, const void* __restrict__ bv,
    u16* __restrict__ qws, u16* __restrict__ kws, u16* __restrict__ vws,
    int n_off, int nshiftp)
{
    __shared__ u16 Wl[64 * 256];   // 32 KB, swizzled bf16 W-slice
    __shared__ int dtf;

    const int t    = threadIdx.x;
    const int bid  = blockIdx.x;
    const int n_w  = bid & ((1 << nshiftp) - 1);
    const int rest = bid >> nshiftp;
    const int g    = rest % 5;        // 0 = q+k, 1..4 = v quarters
    const int it   = rest / 5;        // i-tile (64 i)
    const int n_g  = n_off + n_w;
    const int i0   = it << 6;

    if (t < 64) { int f = detect_f32_wave0(x, t); if (t == 0) dtf = f; }
    __syncthreads();
    const bool isf32 = (dtf != 0);

    // ---- stage W slice (64 rows x 256 cols) into LDS, swizzled bf16 ----
    #pragma unroll
    for (int k = 0; k < 16; ++k) {
        int idx  = t + (k << 8);
        int row  = idx >> 6;            // 0..63 (wave-uniform per k)
        int col4 = (idx & 63) << 2;     // 0..252 step 4
        const void* src; int srow;
        if (g == 0) {
            if (row < 32) { src = Wq; srow = row; }
            else          { src = Wk; srow = row - 32; }
        } else { src = Wv; srow = ((g - 1) << 6) + row; }
        ushort4 h;
        if (isf32) {
            float4 wv = *((const float4*)((const float*)src + srow * 256 + col4));
            h.x = f2bf(wv.x); h.y = f2bf(wv.y); h.z = f2bf(wv.z); h.w = f2bf(wv.w);
        } else {
            h = *((const ushort4*)((const u16*)src + srow * 256 + col4));
        }
        *(ushort4*)&Wl[(row << 8) + (col4 ^ ((row & 7) << 3))] = h;
    }
    __syncthreads();

    const int lane = t & 63;
    const int w    = t >> 6;          // wave -> i-frag
    const int n16  = lane & 15;
    const int quad = lane >> 4;
    const int i_b  = i0 + (w << 4);
    const int i    = i_b + n16;
    const int swz  = (n16 & 7) << 3;

    f32x4 acc[4];
    #pragma unroll
    for (int f = 0; f < 4; ++f) acc[f] = (f32x4){0.f, 0.f, 0.f, 0.f};

    // ---- k-loop: 8 chunks of 32 c; A direct-global, B from LDS ----
    if (isf32) {
        const float* xp = (const float*)x
            + (((size_t)(n_g * 256 + (quad << 3))) << 12) + i;
        float af[8];
        #pragma unroll
        for (int e = 0; e < 8; ++e) af[e] = xp[(size_t)e << 12];
        #pragma unroll
        for (int c8 = 0; c8 < 8; ++c8) {
            bf16x8 a;
            #pragma unroll
            for (int e = 0; e < 8; ++e) a[e] = (short)f2bf(af[e]);
            if (c8 < 7) {
                const float* xn = xp + (((size_t)(c8 + 1) << 5) << 12);
                #pragma unroll
                for (int e = 0; e < 8; ++e) af[e] = xn[(size_t)e << 12];
            }
            const int c0 = c8 << 5;
            #pragma unroll
            for (int f = 0; f < 4; ++f) {
                const int brow = (f << 4) + n16;
                bf16x8 b = *(const bf16x8*)
                    &Wl[(brow << 8) + ((c0 + (quad << 3)) ^ swz)];
                acc[f] = __builtin_amdgcn_mfma_f32_16x16x32_bf16(a, b, acc[f], 0, 0, 0);
            }
        }
    } else {
        const u16* xp = (const u16*)x
            + (((size_t)(n_g * 256 + (quad << 3))) << 12) + i;
        u16 af[8];
        #pragma unroll
        for (int e = 0; e < 8; ++e) af[e] = xp[(size_t)e << 12];
        #pragma unroll
        for (int c8 = 0; c8 < 8; ++c8) {
            bf16x8 a;
            #pragma unroll
            for (int e = 0; e < 8; ++e) a[e] = (short)af[e];
            if (c8 < 7) {
                const u16* xn = xp + (((size_t)(c8 + 1) << 5) << 12);
                #pragma unroll
                for (int e = 0; e < 8; ++e) af[e] = xn[(size_t)e << 12];
            }
            const int c0 = c8 << 5;
            #pragma unroll
            for (int f = 0; f < 4; ++f) {
                const int brow = (f << 4) + n16;
                bf16x8 b = *(const bf16x8*)
                    &Wl[(brow << 8) + ((c0 + (quad << 3)) ^ swz)];
                acc[f] = __builtin_amdgcn_mfma_f32_16x16x32_bf16(a, b, acc[f], 0, 0, 0);
            }
        }
    }

    // ---- epilogue: D frag is (col = n16 = och-local, row = quad*4+r = i) ----
    if (g == 0) {
        #pragma unroll
        for (int f = 0; f < 4; ++f) {
            const int ol   = (f << 4) + n16;     // 0..63
            const bool isq = (ol < 32);
            const int och  = isq ? ol : (ol - 32);
            float bias;
            if (isf32) bias = ((const float*)(isq ? bq : bk))[och];
            else       bias = bf2f(((const u16*)(isq ? bq : bk))[och]);
            u16* dst = (isq ? qws : kws) + (((size_t)n_w) << 17) + och;
            const float scale = isq ? LOG2E : 1.0f;
            #pragma unroll
            for (int r = 0; r < 4; ++r) {
                const int ii = i_b + (quad << 2) + r;
                dst[(size_t)ii << 5] = f2bf((acc[f][r] + bias) * scale);
            }
        }
    } else {
        #pragma unroll
        for (int f = 0; f < 4; ++f) {
            const int c = ((g - 1) << 6) + (f << 4) + n16;   // c&15 == n16
            float bias = isf32 ? ((const float*)bv)[c]
                               : bf2f(((const u16*)bv)[c]);
            const int i4 = i_b + (quad << 2);
            ushort4 h;
            h.x = f2bf(acc[f][0] + bias);
            h.y = f2bf(acc[f][1] + bias);
            h.z = f2bf(acc[f][2] + bias);
            h.w = f2bf(acc[f][3] + bias);
            const size_t addr = ((size_t)n_w << 20)
                + ((size_t)(c >> 4) << 16)          // cblk*65536
                + ((size_t)(i4 >> 5) << 9)          // jblk*512
                + (size_t)((((((i4 & 31) >> 3) << 4) + (c & 15)) << 3) + (i4 & 7));
            *(ushort4*)(vws + addr) = h;
        }
    }
}

// ---------------------------------------------------------------------------
// Kernel 2 (v10): 32-row blocks, 512 threads (8 waves), 512 blocks ->
// 2 independent barrier domains per CU (barrier-drain overlap; grid 256 was
// exactly 1 block/CU in lockstep). Each wave owns the FULL K=64 accumulation
// (both j-halves) -> jq-combine Dbuf epilogue eliminated; acc stores direct
// (4 consecutive q per lane = 64B segments). S MFMA C-init = -EXP_OFF.
// S: wave (qsub_s 0..1, jsub 0..3). PV: wave cq=w -> 32 c, full 64 j.
// ---------------------------------------------------------------------------
__global__ __launch_bounds__(512) void flash_mfma7(
    const u16* __restrict__ qws, const u16* __restrict__ kws,
    const u16* __restrict__ vws, void* __restrict__ out,
    const void* __restrict__ x, int n_off, int nshift)
{
    __shared__ __align__(16) u16 PsA[2 * 32 * 64];   // 8 KB double-buffered P
    __shared__ __align__(16) float lS[32];
    __shared__ int dtf;

    const int t    = threadIdx.x;
    const int lane = t & 63;
    const int w    = t >> 6;          // 0..7
    const int n16  = lane & 15;
    const int quad = lane >> 4;
    const int bid  = blockIdx.x;
    const int n_w  = bid & ((1 << nshift) - 1);
    const int qt   = bid >> nshift;
    const int n_g  = n_off + n_w;
    const int i0   = qt << 5;         // 32 q-rows per block

    if (t < 64) {
        int f = detect_f32_wave0(x, t);
        if (t == 0) dtf = f;
    }
    if (t < 32) lS[t] = 0.f;

    const u16* qb = qws + (((size_t)n_w) << 17);
    const u16* kb = kws + (((size_t)n_w) << 17);
    const u16* vb = vws + (((size_t)n_w) << 20);

    // S decomposition: 2 q-subtiles x 4 j-subtiles = 8 waves
    const int qsub_s = w & 1;
    const int jsub   = w >> 1;
    // PV decomposition: wave cq -> c in [cq*32, cq*32+32), full 64 j
    const int cq = w;

    const bf16x8 qfrag =
        *(const bf16x8*)(qb + ((size_t)(i0 + (qsub_s << 4) + n16) << 5) + (quad << 3));

    f32x4 acc[2][2];
    #pragma unroll
    for (int a = 0; a < 2; ++a)
        #pragma unroll
        for (int b = 0; b < 2; ++b) acc[a][b] = (f32x4){0.f, 0.f, 0.f, 0.f};
    float lp[4] = {0.f, 0.f, 0.f, 0.f};

    const int jcol = (jsub << 4) + n16;
    const int j8   = jcol >> 3;
    const int jlo  = jcol & 7;

    // Pre-fragmented V: 4 frag pointers (cs 0..1 x jh 0..1); tile step 1024.
    const u16* vfp[2][2];
    #pragma unroll
    for (int cs = 0; cs < 2; ++cs)
        #pragma unroll
        for (int jh = 0; jh < 2; ++jh)
            vfp[cs][jh] = vb + ((size_t)((cq << 1) + cs) << 16)
                             + ((size_t)jh << 9)
                             + ((size_t)((quad << 4) + n16) << 3);

    bf16x8 kreg, vf[2][2];
    const f32x4 zoff = {-EXP_OFF, -EXP_OFF, -EXP_OFF, -EXP_OFF};

    // ---- prologue: S(0) into parity 0; prefetch K(1), V-frags for PV(0) ----
    kreg = *(const bf16x8*)(kb + ((size_t)((jsub << 4) + n16) << 5) + (quad << 3));
    {
        u16* Ps = PsA;
        f32x4 s = __builtin_amdgcn_mfma_f32_16x16x32_bf16(qfrag, kreg, zoff, 0, 0, 0);
        #pragma unroll
        for (int r = 0; r < 4; ++r) {
            const int qrow = (qsub_s << 4) + (quad << 2) + r;
            float p = exp2f(s[r]);
            u32 u = as_u(p) & 0xffff0000u;
            lp[r] += as_f(u);
            Ps[qrow * 64 + ((j8 ^ (qrow & 7)) << 3) + jlo] = (u16)(u >> 16);
        }
        kreg = *(const bf16x8*)(kb + ((size_t)(64 + (jsub << 4) + n16) << 5) + (quad << 3));
        #pragma unroll
        for (int cs = 0; cs < 2; ++cs)
            #pragma unroll
            for (int jh = 0; jh < 2; ++jh)
                vf[cs][jh] = *(const bf16x8*)(vfp[cs][jh]);
    }
    __syncthreads();

    // ---- main loop: ONE barrier per tile ----
    for (int tile = 1; tile < 64; ++tile) {
        const int par  = tile & 1;
        u16* Psc = PsA + (par << 11);
        u16* Psp = PsA + ((par ^ 1) << 11);

        // PV(tile-1): pa from LDS (prev parity), vf prefetched from global
        bf16x8 pa[2][2];
        #pragma unroll
        for (int qs = 0; qs < 2; ++qs) {
            const int qrow = (qs << 4) + n16;
            #pragma unroll
            for (int jh = 0; jh < 2; ++jh) {
                const int ksw = (jh << 2) + quad;
                pa[qs][jh] = *(const bf16x8*)&Psp[qrow * 64 + ((ksw ^ (qrow & 7)) << 3)];
            }
        }
        #pragma unroll
        for (int qs = 0; qs < 2; ++qs)
            #pragma unroll
            for (int cs = 0; cs < 2; ++cs) {
                acc[qs][cs] = __builtin_amdgcn_mfma_f32_16x16x32_bf16(pa[qs][0], vf[cs][0], acc[qs][cs], 0, 0, 0);
                acc[qs][cs] = __builtin_amdgcn_mfma_f32_16x16x32_bf16(pa[qs][1], vf[cs][1], acc[qs][cs], 0, 0, 0);
            }

        // prefetch V-frags for PV(tile) (used next iteration)
        #pragma unroll
        for (int cs = 0; cs < 2; ++cs)
            #pragma unroll
            for (int jh = 0; jh < 2; ++jh)
                vf[cs][jh] = *(const bf16x8*)(vfp[cs][jh] + ((size_t)tile << 10));

        // S(tile) + softmax + P write
        f32x4 s = __builtin_amdgcn_mfma_f32_16x16x32_bf16(qfrag, kreg, zoff, 0, 0, 0);
        #pragma unroll
        for (int r = 0; r < 4; ++r) {
            const int qrow = (qsub_s << 4) + (quad << 2) + r;
            float p = exp2f(s[r]);
            u32 u = as_u(p) & 0xffff0000u;
            lp[r] += as_f(u);
            Psc[qrow * 64 + ((j8 ^ (qrow & 7)) << 3) + jlo] = (u16)(u >> 16);
        }

        // prefetch K for tile+1
        if (tile < 63) {
            const int j0n = (tile + 1) << 6;
            kreg = *(const bf16x8*)(kb + ((size_t)(j0n + (jsub << 4) + n16) << 5)
                                    + (quad << 3));
        }
        __syncthreads();
    }

    // ---- final PV(63): parity 1, vf holds tile-63 frags ----
    {
        u16* Psp = PsA + (1 << 11);
        bf16x8 pa[2][2];
        #pragma unroll
        for (int qs = 0; qs < 2; ++qs) {
            const int qrow = (qs << 4) + n16;
            #pragma unroll
            for (int jh = 0; jh < 2; ++jh) {
                const int ksw = (jh << 2) + quad;
                pa[qs][jh] = *(const bf16x8*)&Psp[qrow * 64 + ((ksw ^ (qrow & 7)) << 3)];
            }
        }
        #pragma unroll
        for (int qs = 0; qs < 2; ++qs)
            #pragma unroll
            for (int cs = 0; cs < 2; ++cs) {
                acc[qs][cs] = __builtin_amdgcn_mfma_f32_16x16x32_bf16(pa[qs][0], vf[cs][0], acc[qs][cs], 0, 0, 0);
                acc[qs][cs] = __builtin_amdgcn_mfma_f32_16x16x32_bf16(pa[qs][1], vf[cs][1], acc[qs][cs], 0, 0, 0);
            }
    }

    // ---- l reduction (over n16 = 16 j within jsub tile) ----
    #pragma unroll
    for (int r = 0; r < 4; ++r) {
        lp[r] += __shfl_xor(lp[r], 1);
        lp[r] += __shfl_xor(lp[r], 2);
        lp[r] += __shfl_xor(lp[r], 4);
        lp[r] += __shfl_xor(lp[r], 8);
    }
    if (n16 == 0) {
        #pragma unroll
        for (int r = 0; r < 4; ++r)
            atomicAdd(&lS[(qsub_s << 4) + (quad << 2) + r], lp[r]);
    }
    __syncthreads();
    if (t < 32) lS[t] = 1.0f / lS[t];
    const bool isf32 = (dtf != 0);
    __syncthreads();

    // ---- epilogue: direct store (acc complete per wave; no jq combine) ----
    // lane (n16, quad), qs, cs: c = cq*32 + cs*16 + n16; q = qs*16 + quad*4 + r
    #pragma unroll
    for (int qs = 0; qs < 2; ++qs) {
        const float4 rl = *(const float4*)&lS[(qs << 4) + (quad << 2)];
        #pragma unroll
        for (int cs = 0; cs < 2; ++cs) {
            const int c = (cq << 5) + (cs << 4) + n16;
            const int q = i0 + (qs << 4) + (quad << 2);
            const size_t ob = (((size_t)(n_g * 256 + c)) << 12) + q;
            const f32x4 d = acc[qs][cs];
            if (isf32) {
                float4 o = make_float4(d[0] * rl.x, d[1] * rl.y,
                                       d[2] * rl.z, d[3] * rl.w);
                *(float4*)((float*)out + ob) = o;
            } else {
                union { uint2 v; u16 h[4]; } o;
                o.h[0] = f2bf(d[0] * rl.x);
                o.h[1] = f2bf(d[1] * rl.y);
                o.h[2] = f2bf(d[2] * rl.z);
                o.h[3] = f2bf(d[3] * rl.w);
                *(uint2*)((u16*)out + ob) = o.v;
            }
        }
    }
}

extern "C" void kernel_launch(void* const* d_in, const int* in_sizes, int n_in,
                              void* d_out, int out_size, void* d_ws, size_t ws_size,
                              hipStream_t stream)
{
    const void* x  = d_in[0];
    const void* Wq = d_in[1];
    const void* bq = d_in[2];
    const void* Wk = d_in[3];
    const void* bk = d_in[4];
    const void* Wv = d_in[5];
    const void* bv = d_in[6];

    const size_t full_need = (size_t)(4u * 4096u) * (32 + 32 + 256) * 2; // 10 MB
    if (ws_size >= full_need) {
        u16* qws = (u16*)d_ws;
        u16* kws = qws + (size_t)4 * 4096 * 32;
        u16* vws = kws + (size_t)4 * 4096 * 32;
        // proj grid = (it*5 + g)*4 + n  -> bid&3 = batch (XCD affinity)
        qkv_proj_mfma<<<dim3(1280), dim3(256), 0, stream>>>(
            x, Wq, bq, Wk, bk, Wv, bv, qws, kws, vws, 0, 2);
        // flash: 512 blocks (128 q-tiles x 4 batches), bid&3 = batch
        flash_mfma7<<<dim3(512), dim3(512), 0, stream>>>(
            qws, kws, vws, d_out, x, 0, 2);
    } else {
        u16* qws = (u16*)d_ws;
        u16* kws = qws + (size_t)4096 * 32;
        u16* vws = kws + (size_t)4096 * 32;
        for (int n = 0; n < 4; ++n) {
            qkv_proj_mfma<<<dim3(320), dim3(256), 0, stream>>>(
                x, Wq, bq, Wk, bk, Wv, bv, qws, kws, vws, n, 0);
            flash_mfma7<<<dim3(128), dim3(512), 0, stream>>>(
                qws, kws, vws, d_out, x, n, 0);
        }
    }
}

// Round 5
// 150.748 us; speedup vs baseline: 1.0064x; 1.0064x over previous
//
#include <hip/hip_runtime.h>
#include <hip/hip_bf16.h>
#include <stdint.h>
#include <stddef.h>

typedef unsigned short u16;
typedef unsigned int   u32;
typedef __attribute__((ext_vector_type(8))) short bf16x8;  // 8 bf16 = 4 VGPRs
typedef __attribute__((ext_vector_type(4))) float f32x4;   // MFMA C/D

#define LOG2E   1.44269504f
#define EXP_OFF 23.0831206f   // 16 * log2(e)

static __device__ __forceinline__ float bf2f(u16 v) {
    u32 u = ((u32)v) << 16; float f; __builtin_memcpy(&f, &u, 4); return f;
}
static __device__ __forceinline__ u16 f2bf(float f) {
    u32 u; __builtin_memcpy(&u, &f, 4);
    u32 r = (u + 0x7fffu + ((u >> 16) & 1u)) >> 16; return (u16)r;
}
static __device__ __forceinline__ float as_f(u32 u) { float f; __builtin_memcpy(&f, &u, 4); return f; }
static __device__ __forceinline__ u32   as_u(float f) { u32 u; __builtin_memcpy(&u, &f, 4); return u; }

// fp32-vs-bf16 input detection (wave 0)
static __device__ __forceinline__ int detect_f32_wave0(const void* x, int t) {
    const u32* xw = (const u32*)x;
    int bad = 0;
    #pragma unroll
    for (int k = 0; k < 4; ++k) {
        u32 wv = xw[(t << 2) + k];
        int e = (wv >> 7) & 0xff;
        bad += (e >= 160);
    }
    unsigned long long m = __ballot(bad > 0);
    return (__popcll(m) >= 8) ? 1 : 0;
}

// V workspace layout (pre-fragmented for MFMA B-operand, per batch):
//   elem_addr = cblk*65536 + jblk*512 + (quad4*16 + clo)*8 + jlo
//   where c = cblk*16 + clo, j = jblk*32 + quad4*8 + jlo.
// A wave B-frag load (lane = quad*16+n16 reads 16B) is 1KB fully contiguous.

// ---------------------------------------------------------------------------
// Kernel 1 (MFMA proj, unchanged — verified at R1):
// ---------------------------------------------------------------------------
__global__ __launch_bounds__(256) void qkv_proj_mfma(
    const void* __restrict__ x,
    const void* __restrict__ Wq, const void* __restrict__ bq,
    const void* __restrict__ Wk, const void* __restrict__ bk,
    const void* __restrict__ Wv, const void* __restrict__ bv,
    u16* __restrict__ qws, u16* __restrict__ kws, u16* __restrict__ vws,
    int n_off, int nshiftp)
{
    __shared__ u16 Wl[64 * 256];   // 32 KB, swizzled bf16 W-slice
    __shared__ int dtf;

    const int t    = threadIdx.x;
    const int bid  = blockIdx.x;
    const int n_w  = bid & ((1 << nshiftp) - 1);
    const int rest = bid >> nshiftp;
    const int g    = rest % 5;        // 0 = q+k, 1..4 = v quarters
    const int it   = rest / 5;        // i-tile (64 i)
    const int n_g  = n_off + n_w;
    const int i0   = it << 6;

    if (t < 64) { int f = detect_f32_wave0(x, t); if (t == 0) dtf = f; }
    __syncthreads();
    const bool isf32 = (dtf != 0);

    // ---- stage W slice (64 rows x 256 cols) into LDS, swizzled bf16 ----
    #pragma unroll
    for (int k = 0; k < 16; ++k) {
        int idx  = t + (k << 8);
        int row  = idx >> 6;            // 0..63 (wave-uniform per k)
        int col4 = (idx & 63) << 2;     // 0..252 step 4
        const void* src; int srow;
        if (g == 0) {
            if (row < 32) { src = Wq; srow = row; }
            else          { src = Wk; srow = row - 32; }
        } else { src = Wv; srow = ((g - 1) << 6) + row; }
        ushort4 h;
        if (isf32) {
            float4 wv = *((const float4*)((const float*)src + srow * 256 + col4));
            h.x = f2bf(wv.x); h.y = f2bf(wv.y); h.z = f2bf(wv.z); h.w = f2bf(wv.w);
        } else {
            h = *((const ushort4*)((const u16*)src + srow * 256 + col4));
        }
        *(ushort4*)&Wl[(row << 8) + (col4 ^ ((row & 7) << 3))] = h;
    }
    __syncthreads();

    const int lane = t & 63;
    const int w    = t >> 6;          // wave -> i-frag
    const int n16  = lane & 15;
    const int quad = lane >> 4;
    const int i_b  = i0 + (w << 4);
    const int i    = i_b + n16;
    const int swz  = (n16 & 7) << 3;

    f32x4 acc[4];
    #pragma unroll
    for (int f = 0; f < 4; ++f) acc[f] = (f32x4){0.f, 0.f, 0.f, 0.f};

    // ---- k-loop: 8 chunks of 32 c; A direct-global, B from LDS ----
    if (isf32) {
        const float* xp = (const float*)x
            + (((size_t)(n_g * 256 + (quad << 3))) << 12) + i;
        float af[8];
        #pragma unroll
        for (int e = 0; e < 8; ++e) af[e] = xp[(size_t)e << 12];
        #pragma unroll
        for (int c8 = 0; c8 < 8; ++c8) {
            bf16x8 a;
            #pragma unroll
            for (int e = 0; e < 8; ++e) a[e] = (short)f2bf(af[e]);
            if (c8 < 7) {
                const float* xn = xp + (((size_t)(c8 + 1) << 5) << 12);
                #pragma unroll
                for (int e = 0; e < 8; ++e) af[e] = xn[(size_t)e << 12];
            }
            const int c0 = c8 << 5;
            #pragma unroll
            for (int f = 0; f < 4; ++f) {
                const int brow = (f << 4) + n16;
                bf16x8 b = *(const bf16x8*)
                    &Wl[(brow << 8) + ((c0 + (quad << 3)) ^ swz)];
                acc[f] = __builtin_amdgcn_mfma_f32_16x16x32_bf16(a, b, acc[f], 0, 0, 0);
            }
        }
    } else {
        const u16* xp = (const u16*)x
            + (((size_t)(n_g * 256 + (quad << 3))) << 12) + i;
        u16 af[8];
        #pragma unroll
        for (int e = 0; e < 8; ++e) af[e] = xp[(size_t)e << 12];
        #pragma unroll
        for (int c8 = 0; c8 < 8; ++c8) {
            bf16x8 a;
            #pragma unroll
            for (int e = 0; e < 8; ++e) a[e] = (short)af[e];
            if (c8 < 7) {
                const u16* xn = xp + (((size_t)(c8 + 1) << 5) << 12);
                #pragma unroll
                for (int e = 0; e < 8; ++e) af[e] = xn[(size_t)e << 12];
            }
            const int c0 = c8 << 5;
            #pragma unroll
            for (int f = 0; f < 4; ++f) {
                const int brow = (f << 4) + n16;
                bf16x8 b = *(const bf16x8*)
                    &Wl[(brow << 8) + ((c0 + (quad << 3)) ^ swz)];
                acc[f] = __builtin_amdgcn_mfma_f32_16x16x32_bf16(a, b, acc[f], 0, 0, 0);
            }
        }
    }

    // ---- epilogue: D frag is (col = n16 = och-local, row = quad*4+r = i) ----
    if (g == 0) {
        #pragma unroll
        for (int f = 0; f < 4; ++f) {
            const int ol   = (f << 4) + n16;     // 0..63
            const bool isq = (ol < 32);
            const int och  = isq ? ol : (ol - 32);
            float bias;
            if (isf32) bias = ((const float*)(isq ? bq : bk))[och];
            else       bias = bf2f(((const u16*)(isq ? bq : bk))[och]);
            u16* dst = (isq ? qws : kws) + (((size_t)n_w) << 17) + och;
            const float scale = isq ? LOG2E : 1.0f;
            #pragma unroll
            for (int r = 0; r < 4; ++r) {
                const int ii = i_b + (quad << 2) + r;
                dst[(size_t)ii << 5] = f2bf((acc[f][r] + bias) * scale);
            }
        }
    } else {
        #pragma unroll
        for (int f = 0; f < 4; ++f) {
            const int c = ((g - 1) << 6) + (f << 4) + n16;   // c&15 == n16
            float bias = isf32 ? ((const float*)bv)[c]
                               : bf2f(((const u16*)bv)[c]);
            const int i4 = i_b + (quad << 2);
            ushort4 h;
            h.x = f2bf(acc[f][0] + bias);
            h.y = f2bf(acc[f][1] + bias);
            h.z = f2bf(acc[f][2] + bias);
            h.w = f2bf(acc[f][3] + bias);
            const size_t addr = ((size_t)n_w << 20)
                + ((size_t)(c >> 4) << 16)          // cblk*65536
                + ((size_t)(i4 >> 5) << 9)          // jblk*512
                + (size_t)((((((i4 & 31) >> 3) << 4) + (c & 15)) << 3) + (i4 & 7));
            *(ushort4*)(vws + addr) = h;
        }
    }
}

// --- flash helpers: plain __forceinline__ functions (no lambdas) ---
static __device__ __forceinline__ void s_tile(
    const bf16x8 qfrag, const bf16x8 kr, u16* __restrict__ Ps,
    float* __restrict__ lp, int qbase, int j8, int jlo)
{
    const f32x4 zoff = {-EXP_OFF, -EXP_OFF, -EXP_OFF, -EXP_OFF};
    f32x4 s = __builtin_amdgcn_mfma_f32_16x16x32_bf16(qfrag, kr, zoff, 0, 0, 0);
    #pragma unroll
    for (int r = 0; r < 4; ++r) {
        const int qrow = qbase + r;
        float p = exp2f(s[r]);
        u32 u = as_u(p) & 0xffff0000u;
        lp[r] += as_f(u);
        Ps[qrow * 64 + ((j8 ^ (qrow & 7)) << 3) + jlo] = (u16)(u >> 16);
    }
}

static __device__ __forceinline__ void pv_tile(
    const u16* __restrict__ Ps, const bf16x8 v0, const bf16x8 v1,
    f32x4 acc[4][2], int n16, int ksw)
{
    bf16x8 pa[4];
    #pragma unroll
    for (int qs = 0; qs < 4; ++qs) {
        const int qrow = (qs << 4) + n16;
        pa[qs] = *(const bf16x8*)&Ps[qrow * 64 + ((ksw ^ (qrow & 7)) << 3)];
    }
    #pragma unroll
    for (int qs = 0; qs < 4; ++qs) {
        acc[qs][0] = __builtin_amdgcn_mfma_f32_16x16x32_bf16(pa[qs], v0, acc[qs][0], 0, 0, 0);
        acc[qs][1] = __builtin_amdgcn_mfma_f32_16x16x32_bf16(pa[qs], v1, acc[qs][1], 0, 0, 0);
    }
}

// ---------------------------------------------------------------------------
// Kernel 2 (v11b): v9's proven 16-wave/64-row structure, re-scheduled:
//   - 2 tiles per phase, 4 P buffers (32 KB LDS) -> 32 barriers (was 64)
//   - ALL global loads issued at phase start: V for the two lag tiles
//     (consumed at phase end, ~700cy slack), K prefetched one phase ahead
//   - S-MFMA C operand = -EXP_OFF (no per-r subtract)
// S: wave (qsub_s 0..3, jsub 0..3). PV: wave (cq 0..7 -> 32c, jq 0..1 -> 32j).
// Dbuf combine epilogue as v9 (aliases the 32KB P arena).
// ---------------------------------------------------------------------------
__global__ __launch_bounds__(1024) void flash_mfma8(
    const u16* __restrict__ qws, const u16* __restrict__ kws,
    const u16* __restrict__ vws, void* __restrict__ out,
    const void* __restrict__ x, int n_off, int nshift)
{
    __shared__ __align__(16) u16 PsA[4 * 64 * 64];   // 32 KB: 4 P buffers
    __shared__ __align__(16) float lS[64];
    __shared__ int dtf;
    float* Dbuf = (float*)PsA;                        // epilogue alias

    const int t    = threadIdx.x;
    const int lane = t & 63;
    const int w    = t >> 6;          // 0..15
    const int n16  = lane & 15;
    const int quad = lane >> 4;
    const int bid  = blockIdx.x;
    const int n_w  = bid & ((1 << nshift) - 1);
    const int qt   = bid >> nshift;
    const int n_g  = n_off + n_w;
    const int i0   = qt << 6;

    if (t < 64) {
        int f = detect_f32_wave0(x, t);
        if (t == 0) dtf = f;
        lS[t] = 0.f;
    }

    const u16* qb = qws + (((size_t)n_w) << 17);
    const u16* kb = kws + (((size_t)n_w) << 17);
    const u16* vb = vws + (((size_t)n_w) << 20);

    // S decomposition
    const int qsub_s = w & 3;
    const int jsub   = w >> 2;
    // PV decomposition: 32 c x 32 j per wave
    const int cq = w & 7;
    const int jq = w >> 3;

    const bf16x8 qfrag =
        *(const bf16x8*)(qb + ((size_t)(i0 + (qsub_s << 4) + n16) << 5) + (quad << 3));

    f32x4 acc[4][2];
    #pragma unroll
    for (int a = 0; a < 4; ++a)
        #pragma unroll
        for (int b = 0; b < 2; ++b) acc[a][b] = (f32x4){0.f, 0.f, 0.f, 0.f};
    float lp[4] = {0.f, 0.f, 0.f, 0.f};

    const int jcol  = (jsub << 4) + n16;
    const int j8    = jcol >> 3;
    const int jlo   = jcol & 7;
    const int ksw   = (jq << 2) + quad;
    const int qbase = (qsub_s << 4) + (quad << 2);

    // K pointer: K(T) frag at kp + T*2048 elems
    const u16* kp = kb + ((size_t)((jsub << 4) + n16) << 5) + (quad << 3);
    // Pre-fragmented V: frag(T, cs) at vfp0 + cs*65536 + T*1024 elems
    const u16* vfp0 = vb + ((size_t)(cq << 1) << 16) + ((size_t)jq << 9)
                         + ((size_t)((quad << 4) + n16) << 3);
    const u16* vfp1 = vfp0 + 65536;

    bf16x8 k0, k1, kn0, kn1, vf00, vf01, vf10, vf11;

    // ---- prologue: S(0)->buf0, S(1)->buf1; prefetch K(2),K(3) ----
    k0 = *(const bf16x8*)(kp);
    k1 = *(const bf16x8*)(kp + 2048);
    s_tile(qfrag, k0, PsA,        lp, qbase, j8, jlo);
    s_tile(qfrag, k1, PsA + 4096, lp, qbase, j8, jlo);
    kn0 = *(const bf16x8*)(kp + 2 * 2048);
    kn1 = *(const bf16x8*)(kp + 3 * 2048);
    __syncthreads();

    // ---- main loop: 31 phases, 2 tiles each, ONE barrier per phase ----
    for (int p = 1; p < 32; ++p) {
        // promote K prefetch; issue next-phase K + this-phase V loads FIRST
        k0 = kn0; k1 = kn1;
        if (p < 31) {
            kn0 = *(const bf16x8*)(kp + ((size_t)((p << 1) + 2) << 11));
            kn1 = *(const bf16x8*)(kp + ((size_t)((p << 1) + 3) << 11));
        }
        const size_t tA = (size_t)((p << 1) - 2) << 10;
        const size_t tB = (size_t)((p << 1) - 1) << 10;
        vf00 = *(const bf16x8*)(vfp0 + tA);
        vf01 = *(const bf16x8*)(vfp1 + tA);
        vf10 = *(const bf16x8*)(vfp0 + tB);
        vf11 = *(const bf16x8*)(vfp1 + tB);

        u16* PsW0 = PsA + ((p & 1) << 13);          // bufs {0,1} or {2,3}
        u16* PsW1 = PsW0 + 4096;
        u16* PsR0 = PsA + (((p & 1) << 13) ^ 8192); // the other pair
        u16* PsR1 = PsR0 + 4096;

        // S(2p), S(2p+1): MFMA early, exp/write overlap with PV below
        s_tile(qfrag, k0, PsW0, lp, qbase, j8, jlo);
        s_tile(qfrag, k1, PsW1, lp, qbase, j8, jlo);
        // PV(2p-2), PV(2p-1): pa from LDS, vf loaded above (~700cy slack)
        pv_tile(PsR0, vf00, vf01, acc, n16, ksw);
        pv_tile(PsR1, vf10, vf11, acc, n16, ksw);
        __syncthreads();
    }

    // ---- final PV(62), PV(63): bufs 2,3 ----
    {
        vf00 = *(const bf16x8*)(vfp0 + ((size_t)62 << 10));
        vf01 = *(const bf16x8*)(vfp1 + ((size_t)62 << 10));
        vf10 = *(const bf16x8*)(vfp0 + ((size_t)63 << 10));
        vf11 = *(const bf16x8*)(vfp1 + ((size_t)63 << 10));
        pv_tile(PsA + 2 * 4096, vf00, vf01, acc, n16, ksw);
        pv_tile(PsA + 3 * 4096, vf10, vf11, acc, n16, ksw);
    }

    // ---- l reduction ----
    #pragma unroll
    for (int r = 0; r < 4; ++r) {
        lp[r] += __shfl_xor(lp[r], 1);
        lp[r] += __shfl_xor(lp[r], 2);
        lp[r] += __shfl_xor(lp[r], 4);
        lp[r] += __shfl_xor(lp[r], 8);
    }
    if (n16 == 0) {
        #pragma unroll
        for (int r = 0; r < 4; ++r)
            atomicAdd(&lS[qbase + r], lp[r]);
    }
    __syncthreads();
    if (t < 64) lS[t] = 1.0f / lS[t];
    const bool isf32 = (dtf != 0);

    // ---- epilogue: 4 chunks of 64 c; combine jq-partials in Dbuf, store ----
    for (int chunk = 0; chunk < 4; ++chunk) {
        __syncthreads();   // Dbuf free; rl ready; Ps reads complete (chunk 0)
        if (jq == 1 && (cq >> 1) == chunk) {
            #pragma unroll
            for (int qs = 0; qs < 4; ++qs)
                #pragma unroll
                for (int cs = 0; cs < 2; ++cs)
                    *(f32x4*)&Dbuf[(((cq & 1) << 5) + (cs << 4) + n16) * 68 +
                                   (qs << 4) + (quad << 2)] = acc[qs][cs];
        }
        __syncthreads();
        if (jq == 0 && (cq >> 1) == chunk) {
            #pragma unroll
            for (int qs = 0; qs < 4; ++qs)
                #pragma unroll
                for (int cs = 0; cs < 2; ++cs) {
                    float* p = &Dbuf[(((cq & 1) << 5) + (cs << 4) + n16) * 68 +
                                     (qs << 4) + (quad << 2)];
                    f32x4 d = *(f32x4*)p;
                    d += acc[qs][cs];
                    *(f32x4*)p = d;
                }
        }
        __syncthreads();
        // store: 1024 threads x 4 q
        const int c_l = t >> 4;
        const int qg  = (t & 15) << 2;
        float4 d  = *(float4*)&Dbuf[c_l * 68 + qg];
        float4 rl = *(float4*)&lS[qg];
        const int c_glob = (chunk << 6) + c_l;
        const size_t ob = (((size_t)(n_g * 256 + c_glob)) << 12) + i0 + qg;
        if (isf32) {
            float4 o = make_float4(d.x * rl.x, d.y * rl.y, d.z * rl.z, d.w * rl.w);
            *(float4*)((float*)out + ob) = o;
        } else {
            union { uint2 v; u16 h[4]; } o;
            o.h[0] = f2bf(d.x * rl.x);
            o.h[1] = f2bf(d.y * rl.y);
            o.h[2] = f2bf(d.z * rl.z);
            o.h[3] = f2bf(d.w * rl.w);
            *(uint2*)((u16*)out + ob) = o.v;
        }
    }
}

extern "C" void kernel_launch(void* const* d_in, const int* in_sizes, int n_in,
                              void* d_out, int out_size, void* d_ws, size_t ws_size,
                              hipStream_t stream)
{
    const void* x  = d_in[0];
    const void* Wq = d_in[1];
    const void* bq = d_in[2];
    const void* Wk = d_in[3];
    const void* bk = d_in[4];
    const void* Wv = d_in[5];
    const void* bv = d_in[6];

    const size_t full_need = (size_t)(4u * 4096u) * (32 + 32 + 256) * 2; // 10 MB
    if (ws_size >= full_need) {
        u16* qws = (u16*)d_ws;
        u16* kws = qws + (size_t)4 * 4096 * 32;
        u16* vws = kws + (size_t)4 * 4096 * 32;
        qkv_proj_mfma<<<dim3(1280), dim3(256), 0, stream>>>(
            x, Wq, bq, Wk, bk, Wv, bv, qws, kws, vws, 0, 2);
        flash_mfma8<<<dim3(256), dim3(1024), 0, stream>>>(
            qws, kws, vws, d_out, x, 0, 2);
    } else {
        u16* qws = (u16*)d_ws;
        u16* kws = qws + (size_t)4096 * 32;
        u16* vws = kws + (size_t)4096 * 32;
        for (int n = 0; n < 4; ++n) {
            qkv_proj_mfma<<<dim3(320), dim3(256), 0, stream>>>(
                x, Wq, bq, Wk, bk, Wv, bv, qws, kws, vws, n, 0);
            flash_mfma8<<<dim3(64), dim3(1024), 0, stream>>>(
                qws, kws, vws, d_out, x, n, 0);
        }
    }
}

// Round 6
// 144.281 us; speedup vs baseline: 1.0515x; 1.0448x over previous
//
#include <hip/hip_runtime.h>
#include <hip/hip_bf16.h>
#include <stdint.h>
#include <stddef.h>

typedef unsigned short u16;
typedef unsigned int   u32;
typedef __attribute__((ext_vector_type(8))) short bf16x8;  // 8 bf16 = 4 VGPRs
typedef __attribute__((ext_vector_type(4))) float f32x4;   // MFMA C/D

#define LOG2E   1.44269504f
#define EXP_OFF 23.0831206f   // 16 * log2(e)

static __device__ __forceinline__ float bf2f(u16 v) {
    u32 u = ((u32)v) << 16; float f; __builtin_memcpy(&f, &u, 4); return f;
}
static __device__ __forceinline__ u16 f2bf(float f) {
    u32 u; __builtin_memcpy(&u, &f, 4);
    u32 r = (u + 0x7fffu + ((u >> 16) & 1u)) >> 16; return (u16)r;
}
static __device__ __forceinline__ float as_f(u32 u) { float f; __builtin_memcpy(&f, &u, 4); return f; }
static __device__ __forceinline__ u32   as_u(float f) { u32 u; __builtin_memcpy(&u, &f, 4); return u; }

// fp32-vs-bf16 input detection (wave 0)
static __device__ __forceinline__ int detect_f32_wave0(const void* x, int t) {
    const u32* xw = (const u32*)x;
    int bad = 0;
    #pragma unroll
    for (int k = 0; k < 4; ++k) {
        u32 wv = xw[(t << 2) + k];
        int e = (wv >> 7) & 0xff;
        bad += (e >= 160);
    }
    unsigned long long m = __ballot(bad > 0);
    return (__popcll(m) >= 8) ? 1 : 0;
}

// V workspace layout (pre-fragmented for MFMA B-operand, per batch):
//   elem_addr = cblk*65536 + jblk*512 + (quad4*16 + clo)*8 + jlo
//   where c = cblk*16 + clo, j = jblk*32 + quad4*8 + jlo.
// A wave B-frag load (lane = quad*16+n16 reads 16B) is 1KB fully contiguous.

// ---------------------------------------------------------------------------
// Kernel 1 (MFMA proj, unchanged — verified at R1):
// ---------------------------------------------------------------------------
__global__ __launch_bounds__(256) void qkv_proj_mfma(
    const void* __restrict__ x,
    const void* __restrict__ Wq, const void* __restrict__ bq,
    const void* __restrict__ Wk, const void* __restrict__ bk,
    const void* __restrict__ Wv, const void* __restrict__ bv,
    u16* __restrict__ qws, u16* __restrict__ kws, u16* __restrict__ vws,
    int n_off, int nshiftp)
{
    __shared__ u16 Wl[64 * 256];   // 32 KB, swizzled bf16 W-slice
    __shared__ int dtf;

    const int t    = threadIdx.x;
    const int bid  = blockIdx.x;
    const int n_w  = bid & ((1 << nshiftp) - 1);
    const int rest = bid >> nshiftp;
    const int g    = rest % 5;        // 0 = q+k, 1..4 = v quarters
    const int it   = rest / 5;        // i-tile (64 i)
    const int n_g  = n_off + n_w;
    const int i0   = it << 6;

    if (t < 64) { int f = detect_f32_wave0(x, t); if (t == 0) dtf = f; }
    __syncthreads();
    const bool isf32 = (dtf != 0);

    // ---- stage W slice (64 rows x 256 cols) into LDS, swizzled bf16 ----
    #pragma unroll
    for (int k = 0; k < 16; ++k) {
        int idx  = t + (k << 8);
        int row  = idx >> 6;            // 0..63 (wave-uniform per k)
        int col4 = (idx & 63) << 2;     // 0..252 step 4
        const void* src; int srow;
        if (g == 0) {
            if (row < 32) { src = Wq; srow = row; }
            else          { src = Wk; srow = row - 32; }
        } else { src = Wv; srow = ((g - 1) << 6) + row; }
        ushort4 h;
        if (isf32) {
            float4 wv = *((const float4*)((const float*)src + srow * 256 + col4));
            h.x = f2bf(wv.x); h.y = f2bf(wv.y); h.z = f2bf(wv.z); h.w = f2bf(wv.w);
        } else {
            h = *((const ushort4*)((const u16*)src + srow * 256 + col4));
        }
        *(ushort4*)&Wl[(row << 8) + (col4 ^ ((row & 7) << 3))] = h;
    }
    __syncthreads();

    const int lane = t & 63;
    const int w    = t >> 6;          // wave -> i-frag
    const int n16  = lane & 15;
    const int quad = lane >> 4;
    const int i_b  = i0 + (w << 4);
    const int i    = i_b + n16;
    const int swz  = (n16 & 7) << 3;

    f32x4 acc[4];
    #pragma unroll
    for (int f = 0; f < 4; ++f) acc[f] = (f32x4){0.f, 0.f, 0.f, 0.f};

    // ---- k-loop: 8 chunks of 32 c; A direct-global, B from LDS ----
    if (isf32) {
        const float* xp = (const float*)x
            + (((size_t)(n_g * 256 + (quad << 3))) << 12) + i;
        float af[8];
        #pragma unroll
        for (int e = 0; e < 8; ++e) af[e] = xp[(size_t)e << 12];
        #pragma unroll
        for (int c8 = 0; c8 < 8; ++c8) {
            bf16x8 a;
            #pragma unroll
            for (int e = 0; e < 8; ++e) a[e] = (short)f2bf(af[e]);
            if (c8 < 7) {
                const float* xn = xp + (((size_t)(c8 + 1) << 5) << 12);
                #pragma unroll
                for (int e = 0; e < 8; ++e) af[e] = xn[(size_t)e << 12];
            }
            const int c0 = c8 << 5;
            #pragma unroll
            for (int f = 0; f < 4; ++f) {
                const int brow = (f << 4) + n16;
                bf16x8 b = *(const bf16x8*)
                    &Wl[(brow << 8) + ((c0 + (quad << 3)) ^ swz)];
                acc[f] = __builtin_amdgcn_mfma_f32_16x16x32_bf16(a, b, acc[f], 0, 0, 0);
            }
        }
    } else {
        const u16* xp = (const u16*)x
            + (((size_t)(n_g * 256 + (quad << 3))) << 12) + i;
        u16 af[8];
        #pragma unroll
        for (int e = 0; e < 8; ++e) af[e] = xp[(size_t)e << 12];
        #pragma unroll
        for (int c8 = 0; c8 < 8; ++c8) {
            bf16x8 a;
            #pragma unroll
            for (int e = 0; e < 8; ++e) a[e] = (short)af[e];
            if (c8 < 7) {
                const u16* xn = xp + (((size_t)(c8 + 1) << 5) << 12);
                #pragma unroll
                for (int e = 0; e < 8; ++e) af[e] = xn[(size_t)e << 12];
            }
            const int c0 = c8 << 5;
            #pragma unroll
            for (int f = 0; f < 4; ++f) {
                const int brow = (f << 4) + n16;
                bf16x8 b = *(const bf16x8*)
                    &Wl[(brow << 8) + ((c0 + (quad << 3)) ^ swz)];
                acc[f] = __builtin_amdgcn_mfma_f32_16x16x32_bf16(a, b, acc[f], 0, 0, 0);
            }
        }
    }

    // ---- epilogue: D frag is (col = n16 = och-local, row = quad*4+r = i) ----
    if (g == 0) {
        #pragma unroll
        for (int f = 0; f < 4; ++f) {
            const int ol   = (f << 4) + n16;     // 0..63
            const bool isq = (ol < 32);
            const int och  = isq ? ol : (ol - 32);
            float bias;
            if (isf32) bias = ((const float*)(isq ? bq : bk))[och];
            else       bias = bf2f(((const u16*)(isq ? bq : bk))[och]);
            u16* dst = (isq ? qws : kws) + (((size_t)n_w) << 17) + och;
            const float scale = isq ? LOG2E : 1.0f;
            #pragma unroll
            for (int r = 0; r < 4; ++r) {
                const int ii = i_b + (quad << 2) + r;
                dst[(size_t)ii << 5] = f2bf((acc[f][r] + bias) * scale);
            }
        }
    } else {
        #pragma unroll
        for (int f = 0; f < 4; ++f) {
            const int c = ((g - 1) << 6) + (f << 4) + n16;   // c&15 == n16
            float bias = isf32 ? ((const float*)bv)[c]
                               : bf2f(((const u16*)bv)[c]);
            const int i4 = i_b + (quad << 2);
            ushort4 h;
            h.x = f2bf(acc[f][0] + bias);
            h.y = f2bf(acc[f][1] + bias);
            h.z = f2bf(acc[f][2] + bias);
            h.w = f2bf(acc[f][3] + bias);
            const size_t addr = ((size_t)n_w << 20)
                + ((size_t)(c >> 4) << 16)          // cblk*65536
                + ((size_t)(i4 >> 5) << 9)          // jblk*512
                + (size_t)((((((i4 & 31) >> 3) << 4) + (c & 15)) << 3) + (i4 & 7));
            *(ushort4*)(vws + addr) = h;
        }
    }
}

// ---------------------------------------------------------------------------
// Kernel 2 (v12): v9 (proven 55us) with ONE change — K prefetch double-
// buffered and issued at PHASE START instead of just before the barrier.
// v9 issued K(tile+1) ~100cy before __syncthreads(); the compiler's
// vmcnt(0) drain at the barrier then ate a full L2 latency every tile.
// Now all global issues sit a full phase (~2000cy) ahead of their drain.
// Everything else identical to v9 (R1, 144.5us build).
// ---------------------------------------------------------------------------
__global__ __launch_bounds__(1024) void flash_mfma9(
    const u16* __restrict__ qws, const u16* __restrict__ kws,
    const u16* __restrict__ vws, void* __restrict__ out,
    const void* __restrict__ x, int n_off, int nshift)
{
    __shared__ __align__(16) char arena[17920];
    __shared__ __align__(16) float lS[64];
    __shared__ int dtf;
    u16*   PsA  = (u16*)arena;                 // + par*4096 (elems)
    float* Dbuf = (float*)arena;               // epilogue alias

    const int t    = threadIdx.x;
    const int lane = t & 63;
    const int w    = t >> 6;          // 0..15
    const int n16  = lane & 15;
    const int quad = lane >> 4;
    const int bid  = blockIdx.x;
    const int n_w  = bid & ((1 << nshift) - 1);
    const int qt   = bid >> nshift;
    const int n_g  = n_off + n_w;
    const int i0   = qt << 6;

    if (t < 64) {
        int f = detect_f32_wave0(x, t);
        if (t == 0) dtf = f;
        lS[t] = 0.f;
    }

    const u16* qb = qws + (((size_t)n_w) << 17);
    const u16* kb = kws + (((size_t)n_w) << 17);
    const u16* vb = vws + (((size_t)n_w) << 20);

    // S decomposition
    const int qsub_s = w & 3;
    const int jsub   = w >> 2;
    // PV decomposition: 32 c x 32 j per wave
    const int cq = w & 7;
    const int jq = w >> 3;

    const bf16x8 qfrag =
        *(const bf16x8*)(qb + ((size_t)(i0 + (qsub_s << 4) + n16) << 5) + (quad << 3));

    f32x4 acc[4][2];
    #pragma unroll
    for (int a = 0; a < 4; ++a)
        #pragma unroll
        for (int b = 0; b < 2; ++b) acc[a][b] = (f32x4){0.f, 0.f, 0.f, 0.f};
    float lp[4] = {0.f, 0.f, 0.f, 0.f};

    const int jcol = (jsub << 4) + n16;
    const int j8   = jcol >> 3;
    const int jlo  = jcol & 7;
    const int ksw  = (jq << 2) + quad;

    // K frag pointer: K(T) at kp + T*2048 elems
    const u16* kp = kb + ((size_t)((jsub << 4) + n16) << 5) + (quad << 3);
    // Pre-fragmented V base: cblk = cq*2 (+1 for second frag), jblk = tile*2+jq
    // addr = cblk*65536 + jblk*512 + lane*8; per-tile step = 1024 elems.
    const u16* vfp0 = vb + ((size_t)(cq << 1) << 16) + ((size_t)jq << 9)
                         + ((size_t)((quad << 4) + n16) << 3);
    const u16* vfp1 = vfp0 + 65536;

    bf16x8 kcur, knext, vf0, vf1;

    // ---- prologue: S(0) into parity 0; prefetch K(1), V-frags for PV(0) ----
    kcur = *(const bf16x8*)(kp);
    {
        u16* Ps = PsA;
        const f32x4 z = {0.f, 0.f, 0.f, 0.f};
        f32x4 s = __builtin_amdgcn_mfma_f32_16x16x32_bf16(qfrag, kcur, z, 0, 0, 0);
        #pragma unroll
        for (int r = 0; r < 4; ++r) {
            const int qrow = (qsub_s << 4) + (quad << 2) + r;
            float p = exp2f(s[r] - EXP_OFF);
            u32 u = as_u(p) & 0xffff0000u;
            lp[r] += as_f(u);
            Ps[qrow * 64 + ((j8 ^ (qrow & 7)) << 3) + jlo] = (u16)(u >> 16);
        }
        knext = *(const bf16x8*)(kp + 2048);
        vf0 = *(const bf16x8*)(vfp0);
        vf1 = *(const bf16x8*)(vfp1);
    }
    __syncthreads();

    // ---- main loop: ONE barrier per tile; ALL vmem issued at phase start
    //      or mid-phase, never just before the barrier ----
    for (int tile = 1; tile < 64; ++tile) {
        const int par  = tile & 1;
        u16* Psc = PsA + (par << 12);
        u16* Psp = PsA + ((par ^ 1) << 12);

        // promote K(tile); issue K(tile+1) FIRST (full-phase cover)
        kcur = knext;
        if (tile < 63) {
            knext = *(const bf16x8*)(kp + ((size_t)(tile + 1) << 11));
        }

        // PV(tile-1): pa from LDS, vf from prefetched coalesced global regs
        bf16x8 pa[4];
        #pragma unroll
        for (int qs = 0; qs < 4; ++qs) {
            const int qrow = (qs << 4) + n16;
            pa[qs] = *(const bf16x8*)&Psp[qrow * 64 + ((ksw ^ (qrow & 7)) << 3)];
        }
        #pragma unroll
        for (int qs = 0; qs < 4; ++qs) {
            acc[qs][0] = __builtin_amdgcn_mfma_f32_16x16x32_bf16(pa[qs], vf0, acc[qs][0], 0, 0, 0);
            acc[qs][1] = __builtin_amdgcn_mfma_f32_16x16x32_bf16(pa[qs], vf1, acc[qs][1], 0, 0, 0);
        }

        // prefetch V-frags for PV(tile) (consumed next phase, as v9)
        vf0 = *(const bf16x8*)(vfp0 + ((size_t)tile << 10));
        vf1 = *(const bf16x8*)(vfp1 + ((size_t)tile << 10));

        // S(tile) + softmax + P write (uses kcur, loaded one phase ago)
        const f32x4 z = {0.f, 0.f, 0.f, 0.f};
        f32x4 s = __builtin_amdgcn_mfma_f32_16x16x32_bf16(qfrag, kcur, z, 0, 0, 0);
        #pragma unroll
        for (int r = 0; r < 4; ++r) {
            const int qrow = (qsub_s << 4) + (quad << 2) + r;
            float p = exp2f(s[r] - EXP_OFF);
            u32 u = as_u(p) & 0xffff0000u;
            lp[r] += as_f(u);
            Psc[qrow * 64 + ((j8 ^ (qrow & 7)) << 3) + jlo] = (u16)(u >> 16);
        }

        __syncthreads();
    }

    // ---- final PV(63): parity 1, vf holds jblk of tile 63 ----
    {
        u16* Psp = PsA + (1 << 12);
        bf16x8 pa[4];
        #pragma unroll
        for (int qs = 0; qs < 4; ++qs) {
            const int qrow = (qs << 4) + n16;
            pa[qs] = *(const bf16x8*)&Psp[qrow * 64 + ((ksw ^ (qrow & 7)) << 3)];
        }
        #pragma unroll
        for (int qs = 0; qs < 4; ++qs) {
            acc[qs][0] = __builtin_amdgcn_mfma_f32_16x16x32_bf16(pa[qs], vf0, acc[qs][0], 0, 0, 0);
            acc[qs][1] = __builtin_amdgcn_mfma_f32_16x16x32_bf16(pa[qs], vf1, acc[qs][1], 0, 0, 0);
        }
    }

    // ---- l reduction ----
    #pragma unroll
    for (int r = 0; r < 4; ++r) {
        lp[r] += __shfl_xor(lp[r], 1);
        lp[r] += __shfl_xor(lp[r], 2);
        lp[r] += __shfl_xor(lp[r], 4);
        lp[r] += __shfl_xor(lp[r], 8);
    }
    if (n16 == 0) {
        #pragma unroll
        for (int r = 0; r < 4; ++r)
            atomicAdd(&lS[(qsub_s << 4) + (quad << 2) + r], lp[r]);
    }
    __syncthreads();
    if (t < 64) lS[t] = 1.0f / lS[t];
    const bool isf32 = (dtf != 0);

    // ---- epilogue: 4 chunks of 64 c; combine jq-partials in Dbuf, store ----
    for (int chunk = 0; chunk < 4; ++chunk) {
        __syncthreads();   // Dbuf free; rl ready; Ps reads complete (chunk 0)
        if (jq == 1 && (cq >> 1) == chunk) {
            #pragma unroll
            for (int qs = 0; qs < 4; ++qs)
                #pragma unroll
                for (int cs = 0; cs < 2; ++cs)
                    *(f32x4*)&Dbuf[(((cq & 1) << 5) + (cs << 4) + n16) * 68 +
                                   (qs << 4) + (quad << 2)] = acc[qs][cs];
        }
        __syncthreads();
        if (jq == 0 && (cq >> 1) == chunk) {
            #pragma unroll
            for (int qs = 0; qs < 4; ++qs)
                #pragma unroll
                for (int cs = 0; cs < 2; ++cs) {
                    float* p = &Dbuf[(((cq & 1) << 5) + (cs << 4) + n16) * 68 +
                                     (qs << 4) + (quad << 2)];
                    f32x4 d = *(f32x4*)p;
                    d += acc[qs][cs];
                    *(f32x4*)p = d;
                }
        }
        __syncthreads();
        // store: 1024 threads x 4 q
        const int c_l = t >> 4;
        const int qg  = (t & 15) << 2;
        float4 d  = *(float4*)&Dbuf[c_l * 68 + qg];
        float4 rl = *(float4*)&lS[qg];
        const int c_glob = (chunk << 6) + c_l;
        const size_t ob = (((size_t)(n_g * 256 + c_glob)) << 12) + i0 + qg;
        if (isf32) {
            float4 o = make_float4(d.x * rl.x, d.y * rl.y, d.z * rl.z, d.w * rl.w);
            *(float4*)((float*)out + ob) = o;
        } else {
            union { uint2 v; u16 h[4]; } o;
            o.h[0] = f2bf(d.x * rl.x);
            o.h[1] = f2bf(d.y * rl.y);
            o.h[2] = f2bf(d.z * rl.z);
            o.h[3] = f2bf(d.w * rl.w);
            *(uint2*)((u16*)out + ob) = o.v;
        }
    }
}

extern "C" void kernel_launch(void* const* d_in, const int* in_sizes, int n_in,
                              void* d_out, int out_size, void* d_ws, size_t ws_size,
                              hipStream_t stream)
{
    const void* x  = d_in[0];
    const void* Wq = d_in[1];
    const void* bq = d_in[2];
    const void* Wk = d_in[3];
    const void* bk = d_in[4];
    const void* Wv = d_in[5];
    const void* bv = d_in[6];

    const size_t full_need = (size_t)(4u * 4096u) * (32 + 32 + 256) * 2; // 10 MB
    if (ws_size >= full_need) {
        u16* qws = (u16*)d_ws;
        u16* kws = qws + (size_t)4 * 4096 * 32;
        u16* vws = kws + (size_t)4 * 4096 * 32;
        qkv_proj_mfma<<<dim3(1280), dim3(256), 0, stream>>>(
            x, Wq, bq, Wk, bk, Wv, bv, qws, kws, vws, 0, 2);
        flash_mfma9<<<dim3(256), dim3(1024), 0, stream>>>(
            qws, kws, vws, d_out, x, 0, 2);
    } else {
        u16* qws = (u16*)d_ws;
        u16* kws = qws + (size_t)4096 * 32;
        u16* vws = kws + (size_t)4096 * 32;
        for (int n = 0; n < 4; ++n) {
            qkv_proj_mfma<<<dim3(320), dim3(256), 0, stream>>>(
                x, Wq, bq, Wk, bk, Wv, bv, qws, kws, vws, n, 0);
            flash_mfma9<<<dim3(64), dim3(1024), 0, stream>>>(
                qws, kws, vws, d_out, x, n, 0);
        }
    }
}